// Round 5
// baseline (189.722 us; speedup 1.0000x reference)
//
#include <hip/hip_runtime.h>

typedef _Float16 f16;
typedef __attribute__((ext_vector_type(8))) _Float16 f16x8;
typedef __attribute__((ext_vector_type(4))) float f32x4;

// padded spatial layout: [b][y][x][128ch], y,x in 0..129, zero halo.

__device__ __forceinline__ void g2l16(const void* g, void* l) {
  __builtin_amdgcn_global_load_lds((const __attribute__((address_space(1))) void*)g,
                                   (__attribute__((address_space(3))) void*)l, 16, 0, 0);
}

// conv weight pack: [ky][cc][kx][128 o][4 g][8]; slot g holds chunk g^((o>>1)&3)
__device__ __forceinline__ void pack_conv(const float* __restrict__ src, f16* __restrict__ dst,
                                          long idx, int C) {
  int ci3 = idx & 7;
  int g = (idx >> 3) & 3;
  long t = idx >> 5;
  int o = (int)(t & 127); t >>= 7;
  int kx = (int)(t % 3); t /= 3;
  int nkc = C >> 5;
  int cc = (int)(t % nkc);
  int ky = (int)(t / nkc);
  int c = (cc << 5) + ((g ^ ((o >> 1) & 3)) << 3) + ci3;
  dst[idx] = (f16)src[(((size_t)o * C + c) * 3 + ky) * 3 + kx];
}

__device__ __forceinline__ void halo_zero(f16* __restrict__ buf, long e) {
  int c = (int)(e & 127);
  long t = e >> 7;
  int b = (int)(t / 516);
  int p = (int)(t % 516);
  int y, x;
  if (p < 130)      { y = 0;   x = p; }
  else if (p < 260) { y = 129; x = p - 130; }
  else if (p < 388) { x = 0;   y = p - 259; }
  else              { x = 129; y = p - 387; }
  buf[((size_t)(b * 130 + y) * 130 + x) * 128 + c] = (f16)0.f;
}

// ---- init: NCHW->padded-NHWC (xP, refP) + weight packing + halo zeroing ----
__global__ __launch_bounds__(256) void init_k(const float* __restrict__ x, const float* __restrict__ ref,
                                              const float* __restrict__ w1, const float* __restrict__ w2,
                                              const float* __restrict__ woff, const float* __restrict__ wdef,
                                              f16* __restrict__ W1p, f16* __restrict__ W2p,
                                              f16* __restrict__ Woffp, f16* __restrict__ Wdefp,
                                              f16* __restrict__ xP, f16* __restrict__ refP,
                                              f16* __restrict__ est1, f16* __restrict__ est2) {
  __shared__ __align__(16) f16 T[64][40];
  int tid = threadIdx.x;
  if (blockIdx.x < 4096) {  // transpose
    int bi = blockIdx.x;
    int row = bi & 255, wseg = (bi >> 8) & 1, chunk = bi >> 9;
    int b = row >> 7, h = row & 127;
    int w0 = wseg * 64;
    const float* src = (chunk < 4) ? x : ref;
    f16* dstp = (chunk < 4) ? xP : refP;
    int c0 = (chunk & 3) * 32;
#pragma unroll
    for (int i = 0; i < 2; ++i) {
      int idx = tid + i * 256;
      int c = idx >> 4, g = idx & 15;
      const float4 v = *(const float4*)(src + (((size_t)(b * 128 + c0 + c)) * 128 + h) * 128 + w0 + g * 4);
      T[g * 4 + 0][c] = (f16)v.x;
      T[g * 4 + 1][c] = (f16)v.y;
      T[g * 4 + 2][c] = (f16)v.z;
      T[g * 4 + 3][c] = (f16)v.w;
    }
    __syncthreads();
    int w = tid >> 2, g = tid & 3;
    f16x8 o = *(const f16x8*)&T[w][g * 8];
    *(f16x8*)(dstp + ((size_t)(b * 130 + h + 1) * 130 + w0 + w + 1) * 128 + c0 + g * 8) = o;
    return;
  }
  long idx = (long)(blockIdx.x - 4096) * 256 + tid;
  if (idx < 294912) { pack_conv(w1, W1p, idx, 256); return; }
  idx -= 294912;
  if (idx < 147456) { pack_conv(w2, W2p, idx, 128); return; }
  idx -= 147456;
  if (idx < 36864) {  // Woffp: [ky][cc][kx][32 o][4 g][8], o>=18 zero
    int ci3 = (int)(idx & 7);
    int g = (int)((idx >> 3) & 3);
    int o = (int)((idx >> 5) & 31);
    int t2 = (int)(idx >> 10);
    int kx = t2 % 3; t2 /= 3;
    int cc = t2 & 3, ky = t2 >> 2;
    int c = (cc << 5) + ((g ^ ((o >> 1) & 3)) << 3) + ci3;
    Woffp[idx] = (o < 18) ? (f16)woff[(((size_t)o * 128 + c) * 3 + ky) * 3 + kx] : (f16)0.f;
    return;
  }
  idx -= 36864;
  if (idx < 147456) {  // Wdefp: [t][cc][ofr][lane][8] lane-linear A-frags
    int j = (int)(idx & 7);
    int ln = (int)((idx >> 3) & 63);
    int ofr = (int)((idx >> 9) & 7);
    int cc = (int)((idx >> 12) & 3);
    int t = (int)(idx >> 14);
    int o = ofr * 16 + (ln & 15);
    int c = cc * 32 + (ln >> 4) * 8 + j;
    Wdefp[idx] = (f16)wdef[(((size_t)o * 128 + c) * 3 + t / 3) * 3 + t % 3];
    return;
  }
  idx -= 147456;
  if (idx < 132096) { halo_zero(xP, idx); return; }
  idx -= 132096;
  if (idx < 132096) { halo_zero(refP, idx); return; }
  idx -= 132096;
  if (idx < 132096) { halo_zero(est1, idx); return; }
  idx -= 132096;
  if (idx < 132096) halo_zero(est2, idx);
}

// ---- implicit-GEMM 3x3 conv: block 128px x 128o, wave 64x64 (ratio 0.5) ----
template <int NKC>
__global__ __launch_bounds__(256, 1) void conv_k(const f16* __restrict__ src0,
                                                 const f16* __restrict__ src1,
                                                 const f16* __restrict__ Wp,
                                                 f16* __restrict__ dst) {
  constexpr int S = 3 * NKC;
  const int row = blockIdx.x;
  const int b = row >> 7, h = row & 127;
  __shared__ __align__(16) f16 As[2][130][32];      // 16.25 KB
  __shared__ __align__(16) f16 Bs[2][3][128][32];   // 48 KB
  const int tid = threadIdx.x;
  const int lane = tid & 63, wave = tid >> 6;
  const int l16 = lane & 15, quad = lane >> 4;
  const int wm = (wave & 1) * 64;   // px base
  const int wn = (wave >> 1) * 64;  // o base
  f32x4 acc[4][4] = {};

  auto stage = [&](int s, int buf) {
    int ky = s / NKC, cc = s % NKC;
    const f16* sp = (NKC == 8 && cc >= 4) ? src1 : src0;
    int c0 = (NKC == 8 ? (cc & 3) : cc) * 32;
    const f16* abase = sp + ((size_t)(b * 130 + h + ky) * 130) * 128 + c0;
#pragma unroll
    for (int rr = 0; rr < 2; ++rr) {  // A: 520 chunks of 16B
      int ch = rr * 256 + tid;
      int xx = ch >> 2, g = ch & 3;
      g2l16(abase + (size_t)xx * 128 + ((g ^ ((xx >> 1) & 3)) << 3),
            (char*)&As[buf][0][0] + ch * 16);
    }
    if (tid < 8) {
      int ch = 512 + tid;
      int xx = ch >> 2, g = ch & 3;
      g2l16(abase + (size_t)xx * 128 + ((g ^ ((xx >> 1) & 3)) << 3),
            (char*)&As[buf][0][0] + ch * 16);
    }
    const f16* bbase = Wp + (size_t)(ky * NKC + cc) * (3 * 128 * 32);
#pragma unroll
    for (int rr = 0; rr < 6; ++rr) {  // B: 1536 chunks
      int ch = rr * 256 + tid;
      g2l16(bbase + (size_t)ch * 8, (char*)&Bs[buf][0][0][0] + ch * 16);
    }
  };

  stage(0, 0);
  __syncthreads();
  for (int s = 0; s < S; ++s) {
    if (s + 1 < S) stage(s + 1, (s + 1) & 1);
    const int buf = s & 1;
#pragma unroll
    for (int kx = 0; kx < 3; ++kx) {
      f16x8 bf[4], af[4];
#pragma unroll
      for (int j = 0; j < 4; ++j) {
        int o = wn + j * 16 + l16;
        bf[j] = *(const f16x8*)&Bs[buf][kx][o][(quad ^ ((o >> 1) & 3)) << 3];
      }
#pragma unroll
      for (int i = 0; i < 4; ++i) {
        int xx = wm + i * 16 + l16 + kx;
        af[i] = *(const f16x8*)&As[buf][xx][(quad ^ ((xx >> 1) & 3)) << 3];
      }
#pragma unroll
      for (int i = 0; i < 4; ++i)
#pragma unroll
        for (int j = 0; j < 4; ++j)
          acc[i][j] = __builtin_amdgcn_mfma_f32_16x16x32_f16(af[i], bf[j], acc[i][j], 0, 0, 0);
    }
    __syncthreads();
  }
#pragma unroll
  for (int i = 0; i < 4; ++i)
#pragma unroll
    for (int j = 0; j < 4; ++j) {
      int o = wn + j * 16 + l16;
#pragma unroll
      for (int rr = 0; rr < 4; ++rr) {
        int m = wm + i * 16 + quad * 4 + rr;
        float v = fmaxf(acc[i][j][rr], 0.f);
        dst[((size_t)(b * 130 + h + 1) * 130 + m + 1) * 128 + o] = (f16)v;
      }
    }
}

// ---- offset conv: M=128, N=32 (18 real), fp32 out [row*128+px][32] ----
__global__ __launch_bounds__(256, 3) void conv_off_k(const f16* __restrict__ src,
                                                     const f16* __restrict__ Wp,
                                                     float* __restrict__ dst) {
  const int row = blockIdx.x;
  const int b = row >> 7, h = row & 127;
  __shared__ __align__(16) f16 As[2][130][32];
  __shared__ __align__(16) f16 Bs[2][3][32][32];
  const int tid = threadIdx.x;
  const int lane = tid & 63, wave = tid >> 6;
  const int l16 = lane & 15, quad = lane >> 4;
  const int wmB = wave * 32;
  f32x4 acc[2][2] = {};

  auto stage = [&](int s, int buf) {
    int ky = s >> 2, cc = s & 3;
    const f16* abase = src + ((size_t)(b * 130 + h + ky) * 130) * 128 + cc * 32;
#pragma unroll
    for (int rr = 0; rr < 2; ++rr) {
      int ch = rr * 256 + tid;
      int xx = ch >> 2, g = ch & 3;
      g2l16(abase + (size_t)xx * 128 + ((g ^ ((xx >> 1) & 3)) << 3),
            (char*)&As[buf][0][0] + ch * 16);
    }
    if (tid < 8) {
      int ch = 512 + tid;
      int xx = ch >> 2, g = ch & 3;
      g2l16(abase + (size_t)xx * 128 + ((g ^ ((xx >> 1) & 3)) << 3),
            (char*)&As[buf][0][0] + ch * 16);
    }
    const f16* bbase = Wp + (size_t)(ky * 4 + cc) * (3 * 32 * 32);
    {
      g2l16(bbase + (size_t)tid * 8, (char*)&Bs[buf][0][0][0] + tid * 16);
      if (tid < 128) {
        int ch = 256 + tid;
        g2l16(bbase + (size_t)ch * 8, (char*)&Bs[buf][0][0][0] + ch * 16);
      }
    }
  };

  stage(0, 0);
  __syncthreads();
  for (int s = 0; s < 12; ++s) {
    if (s + 1 < 12) stage(s + 1, (s + 1) & 1);
    const int buf = s & 1;
#pragma unroll
    for (int kx = 0; kx < 3; ++kx) {
      f16x8 bf[2];
#pragma unroll
      for (int j = 0; j < 2; ++j) {
        int o = j * 16 + l16;
        bf[j] = *(const f16x8*)&Bs[buf][kx][o][(quad ^ ((o >> 1) & 3)) << 3];
      }
#pragma unroll
      for (int i = 0; i < 2; ++i) {
        int xx = wmB + i * 16 + l16 + kx;
        f16x8 a = *(const f16x8*)&As[buf][xx][(quad ^ ((xx >> 1) & 3)) << 3];
#pragma unroll
        for (int j = 0; j < 2; ++j)
          acc[i][j] = __builtin_amdgcn_mfma_f32_16x16x32_f16(a, bf[j], acc[i][j], 0, 0, 0);
      }
    }
    __syncthreads();
  }
#pragma unroll
  for (int i = 0; i < 2; ++i)
#pragma unroll
    for (int j = 0; j < 2; ++j)
#pragma unroll
      for (int rr = 0; rr < 4; ++rr) {
        int m = wmB + i * 16 + quad * 4 + rr;
        int o = j * 16 + l16;
        dst[((size_t)row * 128 + m) * 32 + o] = acc[i][j][rr];
      }
}

// ---- deform: weights direct-to-frag from global; Ss dbuf; 1 barrier/tap ----
__global__ __launch_bounds__(256, 3) void deform_k(const f16* __restrict__ refP,
                                                   const float* __restrict__ offb,
                                                   const f16* __restrict__ Wdefp,
                                                   float* __restrict__ out) {
  const int row = blockIdx.x, tile = blockIdx.y;
  const int b = row >> 7, h = row & 127;
  __shared__ __align__(16) f16 Ss[2][64][128];  // 32 KB
  __shared__ int4 meta[9][64];                  // 9 KB
  const int tid = threadIdx.x;
  const int lane = tid & 63, wave = tid >> 6;
  const int l16 = lane & 15, quad = lane >> 4;

  for (int e = tid; e < 576; e += 256) {
    int t = e >> 6, p = e & 63;
    int wg = tile * 64 + p;
    const float2 d = *(const float2*)(offb + ((size_t)row * 128 + wg) * 32 + 2 * t);
    float py = (float)(h + t / 3 - 1) + d.x;
    float px = (float)(wg + t % 3 - 1) + d.y;
    float fy = floorf(py), fx = floorf(px);
    meta[t][p] = make_int4((int)fy, (int)fx, __float_as_int(py - fy), __float_as_int(px - fx));
  }

  auto sample = [&](int t, int buf) {
    const int p = tid >> 2, cg = tid & 3;
    int4 mt = meta[t][p];
    int yp = mt.x + 1, xp = mt.y + 1;  // padded coords
    float wy = __int_as_float(mt.z), wx = __int_as_float(mt.w);
    bool y0v = (unsigned)yp < 130u, y1v = (unsigned)(yp + 1) < 130u;
    bool x0v = (unsigned)xp < 130u, x1v = (unsigned)(xp + 1) < 130u;
    int cy0 = y0v ? yp : 0, cy1 = y1v ? yp + 1 : 0;
    int cx0 = x0v ? xp : 0, cx1 = x1v ? xp + 1 : 0;
    float u0 = (1.f - wy) * (y0v ? 1.f : 0.f), u1 = wy * (y1v ? 1.f : 0.f);
    float s0 = (1.f - wx) * (x0v ? 1.f : 0.f), s1 = wx * (x1v ? 1.f : 0.f);
    f16 h00 = (f16)(u0 * s0), h01 = (f16)(u0 * s1);
    f16 h10 = (f16)(u1 * s0), h11 = (f16)(u1 * s1);
    const size_t bb = (size_t)b * 130;
    const f16* p00 = refP + ((bb + cy0) * 130 + cx0) * 128 + cg * 32;
    const f16* p01 = refP + ((bb + cy0) * 130 + cx1) * 128 + cg * 32;
    const f16* p10 = refP + ((bb + cy1) * 130 + cx0) * 128 + cg * 32;
    const f16* p11 = refP + ((bb + cy1) * 130 + cx1) * 128 + cg * 32;
    f16x8 v00[4], v01[4], v10[4], v11[4];
#pragma unroll
    for (int q = 0; q < 4; ++q) {
      v00[q] = *(const f16x8*)(p00 + q * 8);
      v01[q] = *(const f16x8*)(p01 + q * 8);
      v10[q] = *(const f16x8*)(p10 + q * 8);
      v11[q] = *(const f16x8*)(p11 + q * 8);
    }
#pragma unroll
    for (int q = 0; q < 4; ++q) {
      f16x8 rb = v00[q] * h00 + v01[q] * h01 + v10[q] * h10 + v11[q] * h11;
      int c = cg * 4 + q;
      *(f16x8*)&Ss[buf][p][(c ^ (p & 7)) << 3] = rb;
    }
  };

  f32x4 acc[2][4] = {};
  __syncthreads();  // meta ready
  sample(0, 0);
  __syncthreads();
  for (int t = 0; t < 9; ++t) {
    f16x8 af[4][2];  // weights straight to A-frags (issued before sample gathers)
#pragma unroll
    for (int cc = 0; cc < 4; ++cc)
#pragma unroll
      for (int i = 0; i < 2; ++i)
        af[cc][i] = *(const f16x8*)(Wdefp +
            ((((size_t)t * 4 + cc) * 8 + wave * 2 + i) * 64 + lane) * 8);
    if (t < 8) sample(t + 1, (t + 1) & 1);
    const int buf = t & 1;
#pragma unroll
    for (int cc = 0; cc < 4; ++cc) {
      f16x8 bf[4];
#pragma unroll
      for (int j = 0; j < 4; ++j) {
        int p = j * 16 + l16;
        bf[j] = *(const f16x8*)&Ss[buf][p][((cc * 4 + quad) ^ (p & 7)) << 3];
      }
#pragma unroll
      for (int i = 0; i < 2; ++i)
#pragma unroll
        for (int j = 0; j < 4; ++j)
          acc[i][j] = __builtin_amdgcn_mfma_f32_16x16x32_f16(af[cc][i], bf[j], acc[i][j], 0, 0, 0);
    }
    __syncthreads();
  }
#pragma unroll
  for (int i = 0; i < 2; ++i)
#pragma unroll
    for (int rr = 0; rr < 4; ++rr) {
      int o = wave * 32 + i * 16 + quad * 4 + rr;
#pragma unroll
      for (int j = 0; j < 4; ++j) {
        int wg = tile * 64 + j * 16 + l16;
        out[((size_t)(b * 128 + o) * 128 + h) * 128 + wg] = acc[i][j][rr];
      }
    }
}

extern "C" void kernel_launch(void* const* d_in, const int* in_sizes, int n_in,
                              void* d_out, int out_size, void* d_ws, size_t ws_size,
                              hipStream_t stream) {
  const float* x = (const float*)d_in[0];
  const float* ref = (const float*)d_in[1];
  const float* w1 = (const float*)d_in[2];
  const float* w2 = (const float*)d_in[3];
  const float* woff = (const float*)d_in[4];
  const float* wdef = (const float*)d_in[5];
  float* out = (float*)d_out;
  char* ws = (char*)d_ws;
  f16* xP = (f16*)(ws + 0);              //  8,652,800
  f16* refP = (f16*)(ws + 8652800);      //  8,652,800
  f16* est1 = (f16*)(ws + 17305600);     //  8,652,800
  f16* est2 = (f16*)(ws + 25958400);     //  8,652,800
  float* offb = (float*)(ws + 34611200); //  4,194,304
  f16* W1p = (f16*)(ws + 38805504);      //    589,824
  f16* W2p = (f16*)(ws + 39395328);      //    294,912
  f16* Woffp = (f16*)(ws + 39690240);    //     73,728
  f16* Wdefp = (f16*)(ws + 39763968);    //    294,912

  init_k<<<dim3(8608), 256, 0, stream>>>(x, ref, w1, w2, woff, wdef,
                                         W1p, W2p, Woffp, Wdefp, xP, refP, est1, est2);
  conv_k<8><<<dim3(256), 256, 0, stream>>>(xP, refP, W1p, est1);
  conv_k<4><<<dim3(256), 256, 0, stream>>>(est1, est1, W2p, est2);
  conv_off_k<<<dim3(256), 256, 0, stream>>>(est2, Woffp, offb);
  deform_k<<<dim3(256, 2), 256, 0, stream>>>(refP, offb, Wdefp, out);
}

// Round 6
// 169.052 us; speedup vs baseline: 1.1223x; 1.1223x over previous
//
#include <hip/hip_runtime.h>

typedef _Float16 f16;
typedef __attribute__((ext_vector_type(8))) _Float16 f16x8;
typedef __attribute__((ext_vector_type(4))) float f32x4;

// padded spatial layout: [b][y][x][128ch], y,x in 0..129, zero halo.

__device__ __forceinline__ void g2l16(const void* g, void* l) {
  __builtin_amdgcn_global_load_lds((const __attribute__((address_space(1))) void*)g,
                                   (__attribute__((address_space(3))) void*)l, 16, 0, 0);
}

// conv weight pack: [ky][cc][nb][kx][64 o][4 g][8]; slot g holds chunk g^((o>>1)&3)
__device__ __forceinline__ void pack_conv(const float* __restrict__ src, f16* __restrict__ dst,
                                          long idx, int C) {
  int ci3 = idx & 7;
  int g = (idx >> 3) & 3;
  long t = idx >> 5;
  int o = (int)(t & 63); t >>= 6;
  int kx = (int)(t % 3); t /= 3;
  int nb = (int)(t & 1); t >>= 1;
  int nkc = C >> 5;
  int cc = (int)(t % nkc);
  int ky = (int)(t / nkc);
  int og = nb * 64 + o;
  int c = (cc << 5) + ((g ^ ((o >> 1) & 3)) << 3) + ci3;
  dst[idx] = (f16)src[(((size_t)og * C + c) * 3 + ky) * 3 + kx];
}

__device__ __forceinline__ void halo_zero(f16* __restrict__ buf, long e) {
  int c = (int)(e & 127);
  long t = e >> 7;
  int b = (int)(t / 516);
  int p = (int)(t % 516);
  int y, x;
  if (p < 130)      { y = 0;   x = p; }
  else if (p < 260) { y = 129; x = p - 130; }
  else if (p < 388) { x = 0;   y = p - 259; }
  else              { x = 129; y = p - 387; }
  buf[((size_t)(b * 130 + y) * 130 + x) * 128 + c] = (f16)0.f;
}

// ---- init: NCHW->padded-NHWC (xP, refP) + weight packing + halo zeroing ----
__global__ __launch_bounds__(256) void init_k(const float* __restrict__ x, const float* __restrict__ ref,
                                              const float* __restrict__ w1, const float* __restrict__ w2,
                                              const float* __restrict__ woff, const float* __restrict__ wdef,
                                              f16* __restrict__ W1p, f16* __restrict__ W2p,
                                              f16* __restrict__ Woffp, f16* __restrict__ Wdefp,
                                              f16* __restrict__ xP, f16* __restrict__ refP,
                                              f16* __restrict__ est1, f16* __restrict__ est2) {
  __shared__ __align__(16) f16 T[64][40];
  int tid = threadIdx.x;
  if (blockIdx.x < 4096) {  // transpose
    int bi = blockIdx.x;
    int row = bi & 255, wseg = (bi >> 8) & 1, chunk = bi >> 9;
    int b = row >> 7, h = row & 127;
    int w0 = wseg * 64;
    const float* src = (chunk < 4) ? x : ref;
    f16* dstp = (chunk < 4) ? xP : refP;
    int c0 = (chunk & 3) * 32;
#pragma unroll
    for (int i = 0; i < 2; ++i) {
      int idx = tid + i * 256;
      int c = idx >> 4, g = idx & 15;
      const float4 v = *(const float4*)(src + (((size_t)(b * 128 + c0 + c)) * 128 + h) * 128 + w0 + g * 4);
      T[g * 4 + 0][c] = (f16)v.x;
      T[g * 4 + 1][c] = (f16)v.y;
      T[g * 4 + 2][c] = (f16)v.z;
      T[g * 4 + 3][c] = (f16)v.w;
    }
    __syncthreads();
    int w = tid >> 2, g = tid & 3;
    f16x8 o = *(const f16x8*)&T[w][g * 8];
    *(f16x8*)(dstp + ((size_t)(b * 130 + h + 1) * 130 + w0 + w + 1) * 128 + c0 + g * 8) = o;
    return;
  }
  long idx = (long)(blockIdx.x - 4096) * 256 + tid;
  if (idx < 294912) { pack_conv(w1, W1p, idx, 256); return; }
  idx -= 294912;
  if (idx < 147456) { pack_conv(w2, W2p, idx, 128); return; }
  idx -= 147456;
  if (idx < 36864) {  // Woffp: [ky][cc][kx][32 o][4 g][8], o>=18 zero
    int ci3 = (int)(idx & 7);
    int g = (int)((idx >> 3) & 3);
    int o = (int)((idx >> 5) & 31);
    int t2 = (int)(idx >> 10);
    int kx = t2 % 3; t2 /= 3;
    int cc = t2 & 3, ky = t2 >> 2;
    int c = (cc << 5) + ((g ^ ((o >> 1) & 3)) << 3) + ci3;
    Woffp[idx] = (o < 18) ? (f16)woff[(((size_t)o * 128 + c) * 3 + ky) * 3 + kx] : (f16)0.f;
    return;
  }
  idx -= 36864;
  if (idx < 147456) {  // Wdefp: [t][cc][ofr][lane][8] lane-linear A-frags
    int j = (int)(idx & 7);
    int ln = (int)((idx >> 3) & 63);
    int ofr = (int)((idx >> 9) & 7);
    int cc = (int)((idx >> 12) & 3);
    int t = (int)(idx >> 14);
    int o = ofr * 16 + (ln & 15);
    int c = cc * 32 + (ln >> 4) * 8 + j;
    Wdefp[idx] = (f16)wdef[(((size_t)o * 128 + c) * 3 + t / 3) * 3 + t % 3];
    return;
  }
  idx -= 147456;
  if (idx < 132096) { halo_zero(xP, idx); return; }
  idx -= 132096;
  if (idx < 132096) { halo_zero(refP, idx); return; }
  idx -= 132096;
  if (idx < 132096) { halo_zero(est1, idx); return; }
  idx -= 132096;
  if (idx < 132096) halo_zero(est2, idx);
}

// ---- implicit-GEMM 3x3 conv: M=128 (full row), N=64, BK=32, dbuf 1-barrier ----
// XCD-aware swizzle: blockIdx%8 = XCD owns a contiguous 32-row band (L2 locality).
template <int NKC>
__global__ __launch_bounds__(256, 3) void conv_k(const f16* __restrict__ src0,
                                                 const f16* __restrict__ src1,
                                                 const f16* __restrict__ Wp,
                                                 f16* __restrict__ dst) {
  constexpr int S = 3 * NKC;
  const int j = blockIdx.x;         // 0..511
  const int xcd = j & 7, ji = j >> 3;
  const int row = xcd * 32 + (ji & 31);  // XCD k: rows [32k, 32k+32)
  const int nb = ji >> 5;
  const int b = row >> 7, h = row & 127;
  __shared__ __align__(16) f16 As[2][130][32];     // 16.25 KB
  __shared__ __align__(16) f16 Bs[2][3][64][32];   // 24 KB
  const int tid = threadIdx.x;
  const int lane = tid & 63, wave = tid >> 6;
  const int l16 = lane & 15, quad = lane >> 4;
  const int wmB = wave * 32;  // wave tile: 32 px x 64 o
  f32x4 acc[2][4] = {};

  auto stage = [&](int s, int buf) {
    int ky = s / NKC, cc = s % NKC;
    const f16* sp = (NKC == 8 && cc >= 4) ? src1 : src0;
    int c0 = (NKC == 8 ? (cc & 3) : cc) * 32;
    const f16* abase = sp + ((size_t)(b * 130 + h + ky) * 130) * 128 + c0;
#pragma unroll
    for (int rr = 0; rr < 2; ++rr) {  // A: 520 chunks of 16B
      int ch = rr * 256 + tid;
      int xx = ch >> 2, g = ch & 3;
      g2l16(abase + (size_t)xx * 128 + ((g ^ ((xx >> 1) & 3)) << 3),
            (char*)&As[buf][0][0] + ch * 16);
    }
    if (tid < 8) {
      int ch = 512 + tid;
      int xx = ch >> 2, g = ch & 3;
      g2l16(abase + (size_t)xx * 128 + ((g ^ ((xx >> 1) & 3)) << 3),
            (char*)&As[buf][0][0] + ch * 16);
    }
    const f16* bbase = Wp + (size_t)((ky * NKC + cc) * 2 + nb) * (3 * 64 * 32);
#pragma unroll
    for (int rr = 0; rr < 3; ++rr) {  // B: 768 chunks
      int ch = rr * 256 + tid;
      g2l16(bbase + (size_t)ch * 8, (char*)&Bs[buf][0][0][0] + ch * 16);
    }
  };

  stage(0, 0);
  __syncthreads();
  for (int s = 0; s < S; ++s) {
    if (s + 1 < S) stage(s + 1, (s + 1) & 1);
    const int buf = s & 1;
#pragma unroll
    for (int kx = 0; kx < 3; ++kx) {
      f16x8 bf[4];
#pragma unroll
      for (int j2 = 0; j2 < 4; ++j2) {
        int o = j2 * 16 + l16;
        bf[j2] = *(const f16x8*)&Bs[buf][kx][o][(quad ^ ((o >> 1) & 3)) << 3];
      }
#pragma unroll
      for (int i = 0; i < 2; ++i) {
        int xx = wmB + i * 16 + l16 + kx;
        f16x8 a = *(const f16x8*)&As[buf][xx][(quad ^ ((xx >> 1) & 3)) << 3];
#pragma unroll
        for (int j2 = 0; j2 < 4; ++j2)
          acc[i][j2] = __builtin_amdgcn_mfma_f32_16x16x32_f16(a, bf[j2], acc[i][j2], 0, 0, 0);
      }
    }
    __syncthreads();
  }
#pragma unroll
  for (int i = 0; i < 2; ++i)
#pragma unroll
    for (int j2 = 0; j2 < 4; ++j2) {
      int o = nb * 64 + j2 * 16 + l16;
#pragma unroll
      for (int rr = 0; rr < 4; ++rr) {
        int m = wmB + i * 16 + quad * 4 + rr;
        float v = fmaxf(acc[i][j2][rr], 0.f);
        dst[((size_t)(b * 130 + h + 1) * 130 + m + 1) * 128 + o] = (f16)v;
      }
    }
}

// ---- offset conv: M=128, N=32 (18 real), fp32 out [row*128+px][32] ----
__global__ __launch_bounds__(256, 3) void conv_off_k(const f16* __restrict__ src,
                                                     const f16* __restrict__ Wp,
                                                     float* __restrict__ dst) {
  const int j = blockIdx.x;  // 0..255
  const int row = (j & 7) * 32 + (j >> 3);  // XCD band swizzle
  const int b = row >> 7, h = row & 127;
  __shared__ __align__(16) f16 As[2][130][32];
  __shared__ __align__(16) f16 Bs[2][3][32][32];
  const int tid = threadIdx.x;
  const int lane = tid & 63, wave = tid >> 6;
  const int l16 = lane & 15, quad = lane >> 4;
  const int wmB = wave * 32;
  f32x4 acc[2][2] = {};

  auto stage = [&](int s, int buf) {
    int ky = s >> 2, cc = s & 3;
    const f16* abase = src + ((size_t)(b * 130 + h + ky) * 130) * 128 + cc * 32;
#pragma unroll
    for (int rr = 0; rr < 2; ++rr) {
      int ch = rr * 256 + tid;
      int xx = ch >> 2, g = ch & 3;
      g2l16(abase + (size_t)xx * 128 + ((g ^ ((xx >> 1) & 3)) << 3),
            (char*)&As[buf][0][0] + ch * 16);
    }
    if (tid < 8) {
      int ch = 512 + tid;
      int xx = ch >> 2, g = ch & 3;
      g2l16(abase + (size_t)xx * 128 + ((g ^ ((xx >> 1) & 3)) << 3),
            (char*)&As[buf][0][0] + ch * 16);
    }
    const f16* bbase = Wp + (size_t)(ky * 4 + cc) * (3 * 32 * 32);
    {
      g2l16(bbase + (size_t)tid * 8, (char*)&Bs[buf][0][0][0] + tid * 16);
      if (tid < 128) {
        int ch = 256 + tid;
        g2l16(bbase + (size_t)ch * 8, (char*)&Bs[buf][0][0][0] + ch * 16);
      }
    }
  };

  stage(0, 0);
  __syncthreads();
  for (int s = 0; s < 12; ++s) {
    if (s + 1 < 12) stage(s + 1, (s + 1) & 1);
    const int buf = s & 1;
#pragma unroll
    for (int kx = 0; kx < 3; ++kx) {
      f16x8 bf[2];
#pragma unroll
      for (int j2 = 0; j2 < 2; ++j2) {
        int o = j2 * 16 + l16;
        bf[j2] = *(const f16x8*)&Bs[buf][kx][o][(quad ^ ((o >> 1) & 3)) << 3];
      }
#pragma unroll
      for (int i = 0; i < 2; ++i) {
        int xx = wmB + i * 16 + l16 + kx;
        f16x8 a = *(const f16x8*)&As[buf][xx][(quad ^ ((xx >> 1) & 3)) << 3];
#pragma unroll
        for (int j2 = 0; j2 < 2; ++j2)
          acc[i][j2] = __builtin_amdgcn_mfma_f32_16x16x32_f16(a, bf[j2], acc[i][j2], 0, 0, 0);
      }
    }
    __syncthreads();
  }
#pragma unroll
  for (int i = 0; i < 2; ++i)
#pragma unroll
    for (int j2 = 0; j2 < 2; ++j2)
#pragma unroll
      for (int rr = 0; rr < 4; ++rr) {
        int m = wmB + i * 16 + quad * 4 + rr;
        int o = j2 * 16 + l16;
        dst[((size_t)row * 128 + m) * 32 + o] = acc[i][j2][rr];
      }
}

// ---- deform: weights direct-to-frag from global; Ss dbuf; 1 barrier/tap ----
__global__ __launch_bounds__(256, 3) void deform_k(const f16* __restrict__ refP,
                                                   const float* __restrict__ offb,
                                                   const f16* __restrict__ Wdefp,
                                                   float* __restrict__ out) {
  const int j = blockIdx.x;  // 0..511
  const int xcd = j & 7, ji = j >> 3;
  const int row = xcd * 32 + (ji & 31);  // XCD band: gathers stay in 4MB L2
  const int tile = ji >> 5;
  const int b = row >> 7, h = row & 127;
  __shared__ __align__(16) f16 Ss[2][64][128];  // 32 KB
  __shared__ int4 meta[9][64];                  // 9 KB
  const int tid = threadIdx.x;
  const int lane = tid & 63, wave = tid >> 6;
  const int l16 = lane & 15, quad = lane >> 4;

  for (int e = tid; e < 576; e += 256) {
    int t = e >> 6, p = e & 63;
    int wg = tile * 64 + p;
    const float2 d = *(const float2*)(offb + ((size_t)row * 128 + wg) * 32 + 2 * t);
    float py = (float)(h + t / 3 - 1) + d.x;
    float px = (float)(wg + t % 3 - 1) + d.y;
    float fy = floorf(py), fx = floorf(px);
    meta[t][p] = make_int4((int)fy, (int)fx, __float_as_int(py - fy), __float_as_int(px - fx));
  }

  auto sample = [&](int t, int buf) {
    const int p = tid >> 2, cg = tid & 3;
    int4 mt = meta[t][p];
    int yp = mt.x + 1, xp = mt.y + 1;  // padded coords
    float wy = __int_as_float(mt.z), wx = __int_as_float(mt.w);
    bool y0v = (unsigned)yp < 130u, y1v = (unsigned)(yp + 1) < 130u;
    bool x0v = (unsigned)xp < 130u, x1v = (unsigned)(xp + 1) < 130u;
    int cy0 = y0v ? yp : 0, cy1 = y1v ? yp + 1 : 0;
    int cx0 = x0v ? xp : 0, cx1 = x1v ? xp + 1 : 0;
    float u0 = (1.f - wy) * (y0v ? 1.f : 0.f), u1 = wy * (y1v ? 1.f : 0.f);
    float s0 = (1.f - wx) * (x0v ? 1.f : 0.f), s1 = wx * (x1v ? 1.f : 0.f);
    f16 h00 = (f16)(u0 * s0), h01 = (f16)(u0 * s1);
    f16 h10 = (f16)(u1 * s0), h11 = (f16)(u1 * s1);
    const size_t bb = (size_t)b * 130;
    const f16* p00 = refP + ((bb + cy0) * 130 + cx0) * 128 + cg * 32;
    const f16* p01 = refP + ((bb + cy0) * 130 + cx1) * 128 + cg * 32;
    const f16* p10 = refP + ((bb + cy1) * 130 + cx0) * 128 + cg * 32;
    const f16* p11 = refP + ((bb + cy1) * 130 + cx1) * 128 + cg * 32;
    f16x8 v00[4], v01[4], v10[4], v11[4];
#pragma unroll
    for (int q = 0; q < 4; ++q) {
      v00[q] = *(const f16x8*)(p00 + q * 8);
      v01[q] = *(const f16x8*)(p01 + q * 8);
      v10[q] = *(const f16x8*)(p10 + q * 8);
      v11[q] = *(const f16x8*)(p11 + q * 8);
    }
#pragma unroll
    for (int q = 0; q < 4; ++q) {
      f16x8 rb = v00[q] * h00 + v01[q] * h01 + v10[q] * h10 + v11[q] * h11;
      int c = cg * 4 + q;
      *(f16x8*)&Ss[buf][p][(c ^ (p & 7)) << 3] = rb;
    }
  };

  f32x4 acc[2][4] = {};
  __syncthreads();  // meta ready
  sample(0, 0);
  __syncthreads();
  for (int t = 0; t < 9; ++t) {
    f16x8 af[4][2];  // weights straight to A-frags (issued before sample gathers)
#pragma unroll
    for (int cc = 0; cc < 4; ++cc)
#pragma unroll
      for (int i = 0; i < 2; ++i)
        af[cc][i] = *(const f16x8*)(Wdefp +
            ((((size_t)t * 4 + cc) * 8 + wave * 2 + i) * 64 + lane) * 8);
    if (t < 8) sample(t + 1, (t + 1) & 1);
    const int buf = t & 1;
#pragma unroll
    for (int cc = 0; cc < 4; ++cc) {
      f16x8 bf[4];
#pragma unroll
      for (int j2 = 0; j2 < 4; ++j2) {
        int p = j2 * 16 + l16;
        bf[j2] = *(const f16x8*)&Ss[buf][p][((cc * 4 + quad) ^ (p & 7)) << 3];
      }
#pragma unroll
      for (int i = 0; i < 2; ++i)
#pragma unroll
        for (int j2 = 0; j2 < 4; ++j2)
          acc[i][j2] = __builtin_amdgcn_mfma_f32_16x16x32_f16(af[cc][i], bf[j2], acc[i][j2], 0, 0, 0);
    }
    __syncthreads();
  }
#pragma unroll
  for (int i = 0; i < 2; ++i)
#pragma unroll
    for (int rr = 0; rr < 4; ++rr) {
      int o = wave * 32 + i * 16 + quad * 4 + rr;
#pragma unroll
      for (int j2 = 0; j2 < 4; ++j2) {
        int wg = tile * 64 + j2 * 16 + l16;
        out[((size_t)(b * 128 + o) * 128 + h) * 128 + wg] = acc[i][j2][rr];
      }
    }
}

extern "C" void kernel_launch(void* const* d_in, const int* in_sizes, int n_in,
                              void* d_out, int out_size, void* d_ws, size_t ws_size,
                              hipStream_t stream) {
  const float* x = (const float*)d_in[0];
  const float* ref = (const float*)d_in[1];
  const float* w1 = (const float*)d_in[2];
  const float* w2 = (const float*)d_in[3];
  const float* woff = (const float*)d_in[4];
  const float* wdef = (const float*)d_in[5];
  float* out = (float*)d_out;
  char* ws = (char*)d_ws;
  f16* xP = (f16*)(ws + 0);              //  8,652,800
  f16* refP = (f16*)(ws + 8652800);      //  8,652,800
  f16* est1 = (f16*)(ws + 17305600);     //  8,652,800
  f16* est2 = (f16*)(ws + 25958400);     //  8,652,800
  float* offb = (float*)(ws + 34611200); //  4,194,304
  f16* W1p = (f16*)(ws + 38805504);      //    589,824
  f16* W2p = (f16*)(ws + 39395328);      //    294,912
  f16* Woffp = (f16*)(ws + 39690240);    //     73,728
  f16* Wdefp = (f16*)(ws + 39763968);    //    294,912

  init_k<<<dim3(8608), 256, 0, stream>>>(x, ref, w1, w2, woff, wdef,
                                         W1p, W2p, Woffp, Wdefp, xP, refP, est1, est2);
  conv_k<8><<<dim3(512), 256, 0, stream>>>(xP, refP, W1p, est1);
  conv_k<4><<<dim3(512), 256, 0, stream>>>(est1, est1, W2p, est2);
  conv_off_k<<<dim3(256), 256, 0, stream>>>(est2, Woffp, offb);
  deform_k<<<dim3(512), 256, 0, stream>>>(refP, offb, Wdefp, out);
}